// Round 1
// baseline (846.872 us; speedup 1.0000x reference)
//
#include <hip/hip_runtime.h>
#include <math.h>

#define NN      100000
#define EE      1600000
#define NPAIRS  800000
#define DIN     128
#define CC      16
#define NITERS  5

// ---------------------------------------------------------------------------
// log_b0 = log_softmax(x @ W + b)   — 16 lanes per node (lane = class)
// ---------------------------------------------------------------------------
__global__ __launch_bounds__(256) void k_logb0(
    const float* __restrict__ x, const float* __restrict__ W,
    const float* __restrict__ b, float* __restrict__ logb0)
{
    int idx  = blockIdx.x * blockDim.x + threadIdx.x;
    int node = idx >> 4;
    int c    = idx & 15;
    if (node >= NN) return;
    const float* xr = x + (long)node * DIN;
    float acc = b[c];
#pragma unroll 8
    for (int k = 0; k < DIN; ++k)
        acc = fmaf(xr[k], W[k * CC + c], acc);
    // log_softmax across the 16 lanes of this node
    float m = acc;
    for (int off = 8; off; off >>= 1) m = fmaxf(m, __shfl_xor(m, off, 16));
    float s = __expf(acc - m);
    for (int off = 8; off; off >>= 1) s += __shfl_xor(s, off, 16);
    logb0[idx] = acc - m - __logf(s);
}

// ---------------------------------------------------------------------------
// logH (16x16 symmetric) from param[136] via tril_indices + log_sigmoid
// ---------------------------------------------------------------------------
__global__ void k_logH(const float* __restrict__ param, float* __restrict__ logH)
{
    int i = threadIdx.x;
    if (i >= CC * (CC + 1) / 2) return;
    int r = 0;
    while ((r + 1) * (r + 2) / 2 <= i) ++r;   // row of tril index i
    int c = i - r * (r + 1) / 2;
    float z  = param[i] * 10.0f;
    float ls = (z >= 0.f) ? -log1pf(__expf(-z)) : z - log1pf(__expf(z));
    logH[r * CC + c] = ls;
    if (r != c) logH[c * CC + r] = ls;        // mirror -> symmetric
}

// ---------------------------------------------------------------------------
// init: msg = -log(C), agg = 0
// ---------------------------------------------------------------------------
__global__ void k_init(float* __restrict__ msg, float* __restrict__ agg)
{
    const float NEGLOGC = -2.772588722239781f;   // -log(16)
    long stride = (long)gridDim.x * blockDim.x;
    long i0 = (long)blockIdx.x * blockDim.x + threadIdx.x;
    for (long j = i0; j < (long)EE * CC; j += stride) msg[j] = NEGLOGC;
    for (long j = i0; j < (long)NN * CC; j += stride) agg[j] = 0.f;
}

// ---------------------------------------------------------------------------
// per-edge-pair message update + scatter into agg.
// 16 lanes per pair (lane = class). Pair owns edges (2p, 2p+1); rv maps
// within the pair, so in-place msg update is race-free.
// ---------------------------------------------------------------------------
__global__ __launch_bounds__(256) void k_edges(
    const int* __restrict__ esrc, const int* __restrict__ edst,
    const int* __restrict__ rv,
    const float* __restrict__ logb, const float* __restrict__ logHg,
    float* __restrict__ msg, float* __restrict__ agg)
{
    __shared__ float sH[CC * CC];
    if (threadIdx.x < CC * CC) sH[threadIdx.x] = logHg[threadIdx.x];
    __syncthreads();

    int lane = threadIdx.x & 15;
    int p = blockIdx.x * (blockDim.x >> 4) + (threadIdx.x >> 4);
    if (p >= NPAIRS) return;

    int e0 = 2 * p, e1 = 2 * p + 1;
    int s0 = esrc[e0], s1 = esrc[e1];
    int d0 = edst[e0], d1 = edst[e1];
    int r0 = rv[e0],   r1 = rv[e1];

    float t0 = logb[(long)s0 * CC + lane] - msg[(long)r0 * CC + lane];
    float t1 = logb[(long)s1 * CC + lane] - msg[(long)r1 * CC + lane];

    float Hc[CC];                       // logH column `lane`: Hc[k] = logH[k][lane]
#pragma unroll
    for (int k = 0; k < CC; ++k) Hc[k] = sH[k * CC + lane];

    float v0[CC], v1[CC];
#pragma unroll
    for (int k = 0; k < CC; ++k) {
        float a0 = __shfl(t0, k, 16);
        float a1 = __shfl(t1, k, 16);
        v0[k] = a0 + Hc[k];
        v1[k] = a1 + Hc[k];
    }
    float m0 = -INFINITY, m1 = -INFINITY;
#pragma unroll
    for (int k = 0; k < CC; ++k) { m0 = fmaxf(m0, v0[k]); m1 = fmaxf(m1, v1[k]); }
    float su0 = 0.f, su1 = 0.f;
#pragma unroll
    for (int k = 0; k < CC; ++k) { su0 += __expf(v0[k] - m0); su1 += __expf(v1[k] - m1); }
    float raw0 = m0 + __logf(su0);
    float raw1 = m1 + __logf(su1);

    // normalize over classes (the 16 lanes)
    float mm0 = raw0, mm1 = raw1;
    for (int off = 8; off; off >>= 1) {
        mm0 = fmaxf(mm0, __shfl_xor(mm0, off, 16));
        mm1 = fmaxf(mm1, __shfl_xor(mm1, off, 16));
    }
    float ss0 = __expf(raw0 - mm0), ss1 = __expf(raw1 - mm1);
    for (int off = 8; off; off >>= 1) {
        ss0 += __shfl_xor(ss0, off, 16);
        ss1 += __shfl_xor(ss1, off, 16);
    }
    float nm0 = raw0 - mm0 - __logf(ss0);
    float nm1 = raw1 - mm1 - __logf(ss1);

    msg[(long)e0 * CC + lane] = nm0;
    msg[(long)e1 * CC + lane] = nm1;
    atomicAdd(&agg[(long)d0 * CC + lane], nm0);
    atomicAdd(&agg[(long)d1 * CC + lane], nm1);
}

// ---------------------------------------------------------------------------
// log_b = log_normalize(agg + log_b0); also resets agg for next iteration
// ---------------------------------------------------------------------------
__global__ __launch_bounds__(256) void k_update(
    const float* __restrict__ logb0, float* __restrict__ agg,
    float* __restrict__ out)
{
    int idx  = blockIdx.x * blockDim.x + threadIdx.x;
    int node = idx >> 4;
    if (node >= NN) return;
    float v = agg[idx] + logb0[idx];
    agg[idx] = 0.f;                      // re-zero for next k_edges
    float m = v;
    for (int off = 8; off; off >>= 1) m = fmaxf(m, __shfl_xor(m, off, 16));
    float s = __expf(v - m);
    for (int off = 8; off; off >>= 1) s += __shfl_xor(s, off, 16);
    out[idx] = v - m - __logf(s);
}

// ---------------------------------------------------------------------------
extern "C" void kernel_launch(void* const* d_in, const int* in_sizes, int n_in,
                              void* d_out, int out_size, void* d_ws, size_t ws_size,
                              hipStream_t stream)
{
    const float* x     = (const float*)d_in[0];
    const float* W     = (const float*)d_in[1];
    const float* b     = (const float*)d_in[2];
    const float* param = (const float*)d_in[3];
    const int*   eidx  = (const int*)d_in[4];
    const int*   rv    = (const int*)d_in[5];
    const int*   esrc  = eidx;
    const int*   edst  = eidx + EE;

    float* ws    = (float*)d_ws;
    float* logH  = ws;                        // 256 floats
    float* logb0 = logH  + 256;               // N*C
    float* logb  = logb0 + (long)NN * CC;     // N*C
    float* agg   = logb  + (long)NN * CC;     // N*C
    float* msg   = agg   + (long)NN * CC;     // E*C  (102.4 MB)
    float* out   = (float*)d_out;

    k_logb0<<<(NN * CC + 255) / 256, 256, 0, stream>>>(x, W, b, logb0);
    k_logH <<<1, 256, 0, stream>>>(param, logH);
    k_init <<<2048, 256, 0, stream>>>(msg, agg);

    const float* curb = logb0;                // iteration 0 reads log_b0 directly
    for (int it = 0; it < NITERS; ++it) {
        k_edges<<<NPAIRS / 16, 256, 0, stream>>>(esrc, edst, rv, curb, logH, msg, agg);
        float* dst = (it == NITERS - 1) ? out : logb;
        k_update<<<(NN * CC + 255) / 256, 256, 0, stream>>>(logb0, agg, dst);
        curb = dst;
    }
}